// Round 4
// baseline (719.769 us; speedup 1.0000x reference)
//
#include <hip/hip_runtime.h>
#include <math.h>

// Cross-entropy: out = -1/B * sum_b log_softmax(pred)[b, target[b]]
// pred: [B=4096, C=32000] f32; target: [B] i32; out: scalar f32.
//
// R4: DIAGNOSTIC build (deliberate, controlled slowdown). R0 vs R3 proved kernel
// structure is irrelevant to dur_us; the decomposition of dur_us is unverified.
// This kernel reads every row TWICE in two separated NT passes (pass2 via an
// opaque pointer so the compiler cannot CSE the loads; NT pass1 doesn't allocate
// L3 and 524 MB streams between touch and re-touch, so pass2 re-misses to HBM).
// Result is bitwise identical to one pass: s1 == s2 exactly => (s1+s2)*0.5 == s1.
//
// Pre-committed predictions:
//   world (a) kernel~300us @1.8TB/s: dur_us -> ~900-930, ce_row_loss enters top-5
//   world (b) kernel~90-150us near read roofline: dur_us -> ~710-780, top-5 all fills
// Either way the delta measures the kernel's true HBM read time.

#define NCLS 32000
#define NROW 4096
#define N4   (NCLS / 4)   // 8000 f4 per row; per lane 125 f4 = 25 x 5-deep

typedef float f4 __attribute__((ext_vector_type(4)));

#define NTLOAD(p) __builtin_nontemporal_load(p)

__device__ __forceinline__ float exp4sum(f4 v) {
    return (__expf(v.x) + __expf(v.y)) + (__expf(v.z) + __expf(v.w));
}

__device__ __forceinline__ float row_pass(const f4* __restrict__ row4, int lane) {
    const f4* p = row4 + lane;
    // opaque pointer: block CSE across passes
    asm volatile("" : "+v"(p));

    f4 a0 = NTLOAD(p);
    f4 a1 = NTLOAD(p + 64);
    f4 a2 = NTLOAD(p + 128);
    f4 a3 = NTLOAD(p + 192);
    f4 a4 = NTLOAD(p + 256);
    p += 320;

    float s0 = 0.f, s1 = 0.f, s2 = 0.f, s3 = 0.f, s4 = 0.f;
    for (int it = 1; it < 25; ++it, p += 320) {
        f4 b0 = NTLOAD(p);
        f4 b1 = NTLOAD(p + 64);
        f4 b2 = NTLOAD(p + 128);
        f4 b3 = NTLOAD(p + 192);
        f4 b4 = NTLOAD(p + 256);
        s0 += exp4sum(a0);
        s1 += exp4sum(a1);
        s2 += exp4sum(a2);
        s3 += exp4sum(a3);
        s4 += exp4sum(a4);
        a0 = b0; a1 = b1; a2 = b2; a3 = b3; a4 = b4;
    }
    s0 += exp4sum(a0);
    s1 += exp4sum(a1);
    s2 += exp4sum(a2);
    s3 += exp4sum(a3);
    s4 += exp4sum(a4);
    return ((s0 + s1) + (s2 + s3)) + s4;
}

__global__ __launch_bounds__(256, 8) void ce_row_loss(const float* __restrict__ pred,
                                                      const int* __restrict__ target,
                                                      float* __restrict__ row_loss) {
    const int tid  = threadIdx.x;
    const int lane = tid & 63;
    const int wid  = tid >> 6;
    const int row_i = blockIdx.x * 4 + wid;   // one wave per row

    const float* row = pred + (size_t)row_i * NCLS;
    const f4* row4 = reinterpret_cast<const f4*>(row);

    // PASS 1 and PASS 2: identical computation, identical order -> s1 == s2 bitwise.
    float sA = row_pass(row4, lane);
    float sB = row_pass(row4, lane);
    float s = (sA + sB) * 0.5f;   // == sA exactly in f32

    for (int off = 32; off; off >>= 1) s += __shfl_down(s, off, 64);

    if (lane == 0) {
        const int t = target[row_i];
        const float xt = row[t];
        row_loss[row_i] = __logf(s) - xt;
    }
}

__global__ __launch_bounds__(256) void ce_reduce(const float* __restrict__ row_loss,
                                                 float* __restrict__ out) {
    const f4* rl4 = reinterpret_cast<const f4*>(row_loss);  // NROW/4 = 1024 f4
    float acc = 0.0f;
    for (int i = threadIdx.x; i < NROW / 4; i += 256) {
        f4 v = rl4[i];
        acc += (v.x + v.y) + (v.z + v.w);
    }
    for (int off = 32; off; off >>= 1) acc += __shfl_down(acc, off, 64);
    __shared__ float sacc[4];
    if ((threadIdx.x & 63) == 0) sacc[threadIdx.x >> 6] = acc;
    __syncthreads();
    if (threadIdx.x == 0) {
        out[0] = (sacc[0] + sacc[1] + sacc[2] + sacc[3]) / (float)NROW;
    }
}

extern "C" void kernel_launch(void* const* d_in, const int* in_sizes, int n_in,
                              void* d_out, int out_size, void* d_ws, size_t ws_size,
                              hipStream_t stream) {
    const float* pred = (const float*)d_in[0];
    const int* target = (const int*)d_in[1];
    float* out = (float*)d_out;
    float* row_loss = (float*)d_ws;  // NROW floats = 16 KB scratch

    ce_row_loss<<<NROW / 4, 256, 0, stream>>>(pred, target, row_loss);
    ce_reduce<<<1, 256, 0, stream>>>(row_loss, out);
}